// Round 9
// baseline (438.191 us; speedup 1.0000x reference)
//
#include <hip/hip_runtime.h>
#include <hip/hip_bf16.h>

typedef unsigned short u16;
typedef unsigned int u32;
typedef __attribute__((ext_vector_type(8))) short short8;
typedef __attribute__((ext_vector_type(8))) unsigned short ushort8v;
typedef __attribute__((ext_vector_type(4))) unsigned short ushort4v;
typedef __attribute__((ext_vector_type(4))) float f32x4;

static constexpr int B_ = 2, S_ = 4096, D_ = 1024, H_ = 16, HG_ = 2, W_ = 128, DFF_ = 4096;
static constexpr int HL_ = H_ - HG_;   // 14 local heads
static constexpr int M_ = B_ * S_;     // 8192 rows
static constexpr int NCH_ = 4;         // KV chunks for global-head split

static __device__ __forceinline__ u16 f2b(float f) {
    u32 u = __builtin_bit_cast(u32, f);
    u32 r = (u + 0x7fffu + ((u >> 16) & 1u)) >> 16;   // RNE
    return (u16)r;
}
static __device__ __forceinline__ float b2f(u16 b) {
    return __builtin_bit_cast(float, (u32)b << 16);
}

// ---------------- f32 -> bf16 convert (vectorized) ----------------
__global__ __launch_bounds__(256) void k_f32_to_bf16(const float* __restrict__ src,
                                                     u16* __restrict__ dst, int n4) {
    int i = blockIdx.x * 256 + threadIdx.x;
    if (i >= n4) return;
    float4 v = reinterpret_cast<const float4*>(src)[i];
    ushort4v o; o[0] = f2b(v.x); o[1] = f2b(v.y); o[2] = f2b(v.z); o[3] = f2b(v.w);
    reinterpret_cast<ushort4v*>(dst)[i] = o;
}

// ---------------- weight transpose+convert: W[K][N] f32 -> WT[ro+N][K] bf16 ----------------
__global__ __launch_bounds__(256) void k_transpose_bf16(const float* __restrict__ src,
                                                        u16* __restrict__ dst,
                                                        int K, int N, int ro) {
    __shared__ float tile[32][33];
    const int tx = threadIdx.x & 31, ty = threadIdx.x >> 5;  // 32x8
    const int bx = blockIdx.x, by = blockIdx.y;
#pragma unroll
    for (int jj = 0; jj < 4; ++jj) {
        int kk = by * 32 + ty + jj * 8;
        int nn = bx * 32 + tx;
        tile[ty + jj * 8][tx] = src[(size_t)kk * N + nn];
    }
    __syncthreads();
#pragma unroll
    for (int jj = 0; jj < 4; ++jj) {
        int nn = bx * 32 + ty + jj * 8;
        int kk = by * 32 + tx;
        dst[(size_t)(ro + nn) * K + kk] = f2b(tile[tx][ty + jj * 8]);
    }
}

// ---------------- V transpose: qkv V-cols -> vT[(b*H+h)*64 + d][S] bf16 ----------------
__global__ __launch_bounds__(256) void k_transpose_v(const u16* __restrict__ qkv,
                                                     u16* __restrict__ vT) {
    __shared__ u16 tile[32][33];
    const int tx = threadIdx.x & 31, ty = threadIdx.x >> 5;  // 32x8
    const int s0 = blockIdx.x * 32;
    const int d0 = blockIdx.y * 32;
    const int bh = blockIdx.z;
    const int b = bh >> 4, h = bh & 15;
#pragma unroll
    for (int jj = 0; jj < 4; ++jj) {
        int srow = s0 + ty + jj * 8;
        tile[ty + jj * 8][tx] = qkv[(size_t)(b * S_ + srow) * 3072 + 2048 + h * 64 + d0 + tx];
    }
    __syncthreads();
#pragma unroll
    for (int jj = 0; jj < 4; ++jj) {
        int d = d0 + ty + jj * 8;
        vT[(size_t)((b * H_ + h) * 64 + d) * S_ + s0 + tx] = tile[tx][ty + jj * 8];
    }
}

__global__ void k_pack_bias3(const float* __restrict__ a, const float* __restrict__ b,
                             const float* __restrict__ c, float* __restrict__ dst) {
    int i = blockIdx.x * 256 + threadIdx.x;
    if (i >= 3072) return;
    dst[i] = i < 1024 ? a[i] : (i < 2048 ? b[i - 1024] : c[i - 2048]);
}

#define GLDS16(gp, lp) __builtin_amdgcn_global_load_lds( \
    (const __attribute__((address_space(1))) void*)(gp),  \
    (__attribute__((address_space(3))) void*)(lp), 16, 0, 0)

// ---------------- bf16 MFMA GEMM, BM x 256 tile, BK=64, 8 waves ----------------
// r8-proven 2-barrier loop + granule XOR swizzle, widened to BN=256 (and BM=256 for
// big-N GEMMs) to halve L2->LDS staging bytes per FLOP — r8's fitted c(bytes) model
// says staging traffic, not scheduling, is the util limiter (28->32% from BK=32->64;
// c scaled with bytes). 512 threads, 2x4 waves, each wave (BM/2)x64 output.
// Row pitch 128B; swizzle gl = granule ^ (row&7) on BOTH sides (rule #21).
template <int BM, bool LEAKY, bool OUTF, bool OUTB>
__global__ __launch_bounds__(512, 2) void k_gemm2(const u16* __restrict__ A, const u16* __restrict__ Bt,
                                                  const float* __restrict__ bias,
                                                  float* __restrict__ Cf, u16* __restrict__ Cb,
                                                  int M, int N, int K) {
    constexpr int MR = BM / 32;            // m-frags per wave (4 or 8)
    constexpr int AJ = BM / 64;            // A gloads per thread per step (2 or 4)
    __shared__ __align__(16) u16 lA[BM * 64];
    __shared__ __align__(16) u16 lB[256 * 64];
    const int tid = threadIdx.x;
    const int lane = tid & 63, wave = tid >> 6;
    const int wm = wave >> 2, wn = wave & 3;    // 2 x 4
    const int m0 = blockIdx.x * BM, n0 = blockIdx.y * 256;

    f32x4 acc[MR][4];
#pragma unroll
    for (int i = 0; i < MR; ++i)
#pragma unroll
        for (int j = 0; j < 4; ++j)
#pragma unroll
            for (int e = 0; e < 4; ++e) acc[i][j][e] = 0.f;

    const int srow = tid >> 3;                  // 0..63 (rows per gload batch)
    const int sgc = (tid & 7) ^ (srow & 7);     // inverse-swizzled source granule
    const int c = lane & 15, g4 = lane >> 4;

    const u16* gA = A + (size_t)(m0 + srow) * K + sgc * 8;
    const u16* gB = Bt + (size_t)(n0 + srow) * K + sgc * 8;

    const char* lAc = reinterpret_cast<const char*>(lA);
    const char* lBc = reinterpret_cast<const char*>(lB);

    for (int k0 = 0; k0 < K; k0 += 64) {
        __syncthreads();
#pragma unroll
        for (int j = 0; j < AJ; ++j)
            GLDS16(gA + k0 + (size_t)j * 64 * K, lA + j * 4096 + wave * 512);
#pragma unroll
        for (int j = 0; j < 4; ++j)
            GLDS16(gB + k0 + (size_t)j * 64 * K, lB + j * 4096 + wave * 512);
        __syncthreads();

#pragma unroll
        for (int ks = 0; ks < 2; ++ks) {
            const int gl = (ks * 4 + g4) ^ (c & 7);
            short8 af[MR], bfr[4];
#pragma unroll
            for (int mi = 0; mi < MR; ++mi) {
                const int r = wm * (BM / 2) + mi * 16 + c;
                af[mi] = *reinterpret_cast<const short8*>(lAc + r * 128 + gl * 16);
            }
#pragma unroll
            for (int ni = 0; ni < 4; ++ni) {
                const int r = wn * 64 + ni * 16 + c;
                bfr[ni] = *reinterpret_cast<const short8*>(lBc + r * 128 + gl * 16);
            }
            __builtin_amdgcn_s_setprio(1);
#pragma unroll
            for (int mi = 0; mi < MR; ++mi)
#pragma unroll
                for (int ni = 0; ni < 4; ++ni)
                    acc[mi][ni] = __builtin_amdgcn_mfma_f32_16x16x32_bf16(af[mi], bfr[ni], acc[mi][ni], 0, 0, 0);
            __builtin_amdgcn_s_setprio(0);
        }
    }

#pragma unroll
    for (int mi = 0; mi < MR; ++mi) {
        const int rowb = m0 + wm * (BM / 2) + mi * 16 + (lane >> 4) * 4;
#pragma unroll
        for (int ni = 0; ni < 4; ++ni) {
            const int col = n0 + wn * 64 + ni * 16 + (lane & 15);
            const float bs = bias[col];
#pragma unroll
            for (int j = 0; j < 4; ++j) {
                float v = acc[mi][ni][j] + bs;
                if (LEAKY) v = v > 0.f ? v : 0.2f * v;
                const size_t idx = (size_t)(rowb + j) * N + col;
                if (OUTF) Cf[idx] = v;
                if (OUTB) Cb[idx] = f2b(v);
            }
        }
    }
}

// ---------------- MFMA flash attention, LOCAL (banded) heads ----------------
__global__ __launch_bounds__(256) void k_attn_local(const u16* __restrict__ qkv,
                                                    const u16* __restrict__ vT,
                                                    u16* __restrict__ out) {
    __shared__ __align__(16) u16 Kl[64][72];
    __shared__ __align__(16) u16 Vl[64][72];
    __shared__ __align__(16) u16 Pl[4][1024];
    const int tid = threadIdx.x, lane = tid & 63, wave = tid >> 6;
    const int c = lane & 15, g = lane >> 4;
    const int b = blockIdx.z, h = blockIdx.y;
    const int q0 = blockIdx.x * 64;
    const int qrow = q0 + wave * 16 + c;

    short8 qf[2];
    {
        const u16* qp = qkv + (size_t)(b * S_ + qrow) * 3072 + h * 64 + g * 8;
        qf[0] = *reinterpret_cast<const short8*>(qp);
        qf[1] = *reinterpret_cast<const short8*>(qp + 32);
    }

    f32x4 acc[4];
#pragma unroll
    for (int dt = 0; dt < 4; ++dt)
#pragma unroll
        for (int j = 0; j < 4; ++j) acc[dt][j] = 0.f;
    float mrow = -1e30f, lrow = 0.f;

    const int t_lo = max(0, q0 - W_) >> 6;
    const int t_hi = min(S_ - 1, q0 + 63 + W_) >> 6;
    u16* pw = Pl[wave];

    for (int t = t_lo; t <= t_hi; ++t) {
        __syncthreads();
#pragma unroll
        for (int it = 0; it < 2; ++it) {
            int L = it * 256 + tid;
            int r = L >> 3, cb = (L & 7) * 8;
            *reinterpret_cast<ushort8v*>(&Kl[r][cb]) =
                *reinterpret_cast<const ushort8v*>(&qkv[(size_t)(b * S_ + t * 64 + r) * 3072 + 1024 + h * 64 + cb]);
            *reinterpret_cast<ushort8v*>(&Vl[r][cb]) =
                *reinterpret_cast<const ushort8v*>(&vT[(size_t)((b * H_ + h) * 64 + r) * S_ + t * 64 + cb]);
        }
        __syncthreads();

        f32x4 s[4];
#pragma unroll
        for (int nt = 0; nt < 4; ++nt)
#pragma unroll
            for (int j = 0; j < 4; ++j) s[nt][j] = 0.f;
        __builtin_amdgcn_s_setprio(1);
#pragma unroll
        for (int kc = 0; kc < 2; ++kc) {
#pragma unroll
            for (int nt = 0; nt < 4; ++nt) {
                short8 kf = *reinterpret_cast<const short8*>(&Kl[nt * 16 + c][kc * 32 + g * 8]);
                s[nt] = __builtin_amdgcn_mfma_f32_16x16x32_bf16(kf, qf[kc], s[nt], 0, 0, 0);
            }
        }
        __builtin_amdgcn_s_setprio(0);

        float p[4][4];
        float tmax = -1e30f;
#pragma unroll
        for (int nt = 0; nt < 4; ++nt)
#pragma unroll
            for (int j = 0; j < 4; ++j) {
                float sv = s[nt][j] * 0.125f;
                int key = t * 64 + nt * 16 + 4 * g + j;
                bool val = (key >= qrow - W_) && (key <= qrow + W_);
                sv = val ? sv : -1e30f;
                p[nt][j] = sv;
                tmax = fmaxf(tmax, sv);
            }
        tmax = fmaxf(tmax, __shfl_xor(tmax, 16));
        tmax = fmaxf(tmax, __shfl_xor(tmax, 32));
        float mnew = fmaxf(mrow, tmax);
        float fac = __expf(mrow - mnew);
        mrow = mnew;
        float psum = 0.f;
#pragma unroll
        for (int nt = 0; nt < 4; ++nt)
#pragma unroll
            for (int j = 0; j < 4; ++j) {
                p[nt][j] = __expf(p[nt][j] - mnew);
                psum += p[nt][j];
            }
        lrow = lrow * fac + psum;
#pragma unroll
        for (int dt = 0; dt < 4; ++dt)
#pragma unroll
            for (int j = 0; j < 4; ++j) acc[dt][j] *= fac;

#pragma unroll
        for (int nt = 0; nt < 4; ++nt)
#pragma unroll
            for (int jp = 0; jp < 2; ++jp) {
                u32 pk = (u32)f2b(p[nt][2 * jp]) | ((u32)f2b(p[nt][2 * jp + 1]) << 16);
                int byteoff = (c << 7) + ((nt * 32 + 8 * g + 4 * jp) ^ ((c & 7) << 4));
                *reinterpret_cast<u32*>(reinterpret_cast<char*>(pw) + byteoff) = pk;
            }
        asm volatile("s_waitcnt lgkmcnt(0)" ::: "memory");

        __builtin_amdgcn_s_setprio(1);
#pragma unroll
        for (int h2 = 0; h2 < 2; ++h2) {
            int rb = (c << 7) + ((h2 * 64 + g * 16) ^ ((c & 7) << 4));
            short8 pa = *reinterpret_cast<const short8*>(reinterpret_cast<char*>(pw) + rb);
#pragma unroll
            for (int dt = 0; dt < 4; ++dt) {
                short8 vf = *reinterpret_cast<const short8*>(&Vl[dt * 16 + c][h2 * 32 + g * 8]);
                acc[dt] = __builtin_amdgcn_mfma_f32_16x16x32_bf16(vf, pa, acc[dt], 0, 0, 0);
            }
        }
        __builtin_amdgcn_s_setprio(0);
    }

    float lfull = lrow + __shfl_xor(lrow, 16);
    lfull += __shfl_xor(lfull, 32);
    const float rinv = 1.0f / lfull;

#pragma unroll
    for (int dt = 0; dt < 4; ++dt) {
        u32 w0 = (u32)f2b(acc[dt][0] * rinv) | ((u32)f2b(acc[dt][1] * rinv) << 16);
        u32 w1 = (u32)f2b(acc[dt][2] * rinv) | ((u32)f2b(acc[dt][3] * rinv) << 16);
        uint2 wv; wv.x = w0; wv.y = w1;
        *reinterpret_cast<uint2*>(out + (size_t)(b * S_ + qrow) * 1024 + h * 64 + dt * 16 + 4 * g) = wv;
    }
}

// ---------------- GLOBAL heads: split-KV partial flash ----------------
__global__ __launch_bounds__(256) void k_attn_global_part(const u16* __restrict__ qkv,
                                                          const u16* __restrict__ vT,
                                                          const float* __restrict__ mask,
                                                          float* __restrict__ po,
                                                          float* __restrict__ ml) {
    __shared__ __align__(16) u16 Kl[64][72];
    __shared__ __align__(16) u16 Vl[64][72];
    __shared__ __align__(16) u16 Pl[4][1024];
    __shared__ float maskl[64];
    const int tid = threadIdx.x, lane = tid & 63, wave = tid >> 6;
    const int c = lane & 15, g = lane >> 4;
    const int b = blockIdx.z;
    const int hh = blockIdx.y >> 2, ch = blockIdx.y & 3;
    const int h = HL_ + hh;
    const int q0 = blockIdx.x * 64;
    const int qrow = q0 + wave * 16 + c;

    short8 qf[2];
    {
        const u16* qp = qkv + (size_t)(b * S_ + qrow) * 3072 + h * 64 + g * 8;
        qf[0] = *reinterpret_cast<const short8*>(qp);
        qf[1] = *reinterpret_cast<const short8*>(qp + 32);
    }

    f32x4 acc[4];
#pragma unroll
    for (int dt = 0; dt < 4; ++dt)
#pragma unroll
        for (int j = 0; j < 4; ++j) acc[dt][j] = 0.f;
    float mrow = -1e30f, lrow = 0.f;
    u16* pw = Pl[wave];

    const int t_lo = ch * (S_ / 64 / NCH_), t_hi = t_lo + (S_ / 64 / NCH_) - 1;
    for (int t = t_lo; t <= t_hi; ++t) {
        __syncthreads();
#pragma unroll
        for (int it = 0; it < 2; ++it) {
            int L = it * 256 + tid;
            int r = L >> 3, cb = (L & 7) * 8;
            *reinterpret_cast<ushort8v*>(&Kl[r][cb]) =
                *reinterpret_cast<const ushort8v*>(&qkv[(size_t)(b * S_ + t * 64 + r) * 3072 + 1024 + h * 64 + cb]);
            *reinterpret_cast<ushort8v*>(&Vl[r][cb]) =
                *reinterpret_cast<const ushort8v*>(&vT[(size_t)((b * H_ + h) * 64 + r) * S_ + t * 64 + cb]);
        }
        if (tid < 64) maskl[tid] = mask[b * S_ + t * 64 + tid] * (-1000.0f);
        __syncthreads();

        f32x4 s[4];
#pragma unroll
        for (int nt = 0; nt < 4; ++nt)
#pragma unroll
            for (int j = 0; j < 4; ++j) s[nt][j] = 0.f;
        __builtin_amdgcn_s_setprio(1);
#pragma unroll
        for (int kc = 0; kc < 2; ++kc) {
#pragma unroll
            for (int nt = 0; nt < 4; ++nt) {
                short8 kf = *reinterpret_cast<const short8*>(&Kl[nt * 16 + c][kc * 32 + g * 8]);
                s[nt] = __builtin_amdgcn_mfma_f32_16x16x32_bf16(kf, qf[kc], s[nt], 0, 0, 0);
            }
        }
        __builtin_amdgcn_s_setprio(0);

        float p[4][4];
        float tmax = -1e30f;
#pragma unroll
        for (int nt = 0; nt < 4; ++nt)
#pragma unroll
            for (int j = 0; j < 4; ++j) {
                float sv = s[nt][j] * 0.125f + maskl[nt * 16 + 4 * g + j];
                p[nt][j] = sv;
                tmax = fmaxf(tmax, sv);
            }
        tmax = fmaxf(tmax, __shfl_xor(tmax, 16));
        tmax = fmaxf(tmax, __shfl_xor(tmax, 32));
        float mnew = fmaxf(mrow, tmax);
        float fac = __expf(mrow - mnew);
        mrow = mnew;
        float psum = 0.f;
#pragma unroll
        for (int nt = 0; nt < 4; ++nt)
#pragma unroll
            for (int j = 0; j < 4; ++j) {
                p[nt][j] = __expf(p[nt][j] - mnew);
                psum += p[nt][j];
            }
        lrow = lrow * fac + psum;
#pragma unroll
        for (int dt = 0; dt < 4; ++dt)
#pragma unroll
            for (int j = 0; j < 4; ++j) acc[dt][j] *= fac;

#pragma unroll
        for (int nt = 0; nt < 4; ++nt)
#pragma unroll
            for (int jp = 0; jp < 2; ++jp) {
                u32 pk = (u32)f2b(p[nt][2 * jp]) | ((u32)f2b(p[nt][2 * jp + 1]) << 16);
                int byteoff = (c << 7) + ((nt * 32 + 8 * g + 4 * jp) ^ ((c & 7) << 4));
                *reinterpret_cast<u32*>(reinterpret_cast<char*>(pw) + byteoff) = pk;
            }
        asm volatile("s_waitcnt lgkmcnt(0)" ::: "memory");

        __builtin_amdgcn_s_setprio(1);
#pragma unroll
        for (int h2 = 0; h2 < 2; ++h2) {
            int rb = (c << 7) + ((h2 * 64 + g * 16) ^ ((c & 7) << 4));
            short8 pa = *reinterpret_cast<const short8*>(reinterpret_cast<char*>(pw) + rb);
#pragma unroll
            for (int dt = 0; dt < 4; ++dt) {
                short8 vf = *reinterpret_cast<const short8*>(&Vl[dt * 16 + c][h2 * 32 + g * 8]);
                acc[dt] = __builtin_amdgcn_mfma_f32_16x16x32_bf16(vf, pa, acc[dt], 0, 0, 0);
            }
        }
        __builtin_amdgcn_s_setprio(0);
    }

    float lfull = lrow + __shfl_xor(lrow, 16);
    lfull += __shfl_xor(lfull, 32);

    float* po_blk = po + ((((size_t)(b * HG_ + hh) * NCH_ + ch) * (S_ / 64) + blockIdx.x) * 4096);
    const int ql = wave * 16 + c;
#pragma unroll
    for (int dt = 0; dt < 4; ++dt)
        *reinterpret_cast<f32x4*>(po_blk + ql * 64 + dt * 16 + 4 * g) = acc[dt];
    if (g == 0) {
        size_t mb = (((size_t)(b * HG_ + hh) * NCH_ + ch) * S_ + q0 + ql) * 2;
        ml[mb] = mrow;
        ml[mb + 1] = lfull;
    }
}

// ---------------- merge split-KV partials -> bf16 attn output ----------------
__global__ __launch_bounds__(256) void k_attn_merge(const float* __restrict__ po,
                                                    const float* __restrict__ ml,
                                                    u16* __restrict__ out) {
    const int qb = blockIdx.x, hh = blockIdx.y, b = blockIdx.z;
    const int t = threadIdx.x;
    const int ql = t >> 2, d0 = (t & 3) * 16;
    const int q = qb * 64 + ql;

    float mv[NCH_], lv[NCH_];
    float M = -1e30f;
#pragma unroll
    for (int ch = 0; ch < NCH_; ++ch) {
        size_t mb = (((size_t)(b * HG_ + hh) * NCH_ + ch) * S_ + q) * 2;
        mv[ch] = ml[mb];
        lv[ch] = ml[mb + 1];
        M = fmaxf(M, mv[ch]);
    }
    float wch[NCH_], L = 0.f;
#pragma unroll
    for (int ch = 0; ch < NCH_; ++ch) {
        wch[ch] = __expf(mv[ch] - M);
        L += wch[ch] * lv[ch];
    }
    const float rL = 1.0f / L;

    float o[16];
#pragma unroll
    for (int i = 0; i < 16; ++i) o[i] = 0.f;
#pragma unroll
    for (int ch = 0; ch < NCH_; ++ch) {
        const float* pb = po + ((((size_t)(b * HG_ + hh) * NCH_ + ch) * (S_ / 64) + qb) * 4096) + ql * 64 + d0;
        const float w = wch[ch];
#pragma unroll
        for (int i = 0; i < 4; ++i) {
            float4 v = reinterpret_cast<const float4*>(pb)[i];
            o[4 * i + 0] += w * v.x; o[4 * i + 1] += w * v.y;
            o[4 * i + 2] += w * v.z; o[4 * i + 3] += w * v.w;
        }
    }
    ushort8v r0, r1;
#pragma unroll
    for (int i = 0; i < 8; ++i) { r0[i] = f2b(o[i] * rL); r1[i] = f2b(o[8 + i] * rL); }
    u16* op = out + (size_t)(b * S_ + q) * 1024 + (HL_ + hh) * 64 + d0;
    *reinterpret_cast<ushort8v*>(op) = r0;
    *reinterpret_cast<ushort8v*>(op + 8) = r1;
}

// ---------------- fused residual + LayerNorm (row = 1024) ----------------
__global__ __launch_bounds__(256) void k_ln(const float* __restrict__ base, const float* __restrict__ delta,
                                            const float* __restrict__ g, const float* __restrict__ bt,
                                            float* __restrict__ outf, u16* __restrict__ outb) {
    __shared__ float red[8];
    const int row = blockIdx.x, tid = threadIdx.x;
    const int lane = tid & 63, wave = tid >> 6;
    float4 xb = reinterpret_cast<const float4*>(base + (size_t)row * 1024)[tid];
    float4 xd = reinterpret_cast<const float4*>(delta + (size_t)row * 1024)[tid];
    float x0 = xb.x + xd.x, x1 = xb.y + xd.y, x2 = xb.z + xd.z, x3 = xb.w + xd.w;
    float s = x0 + x1 + x2 + x3;
#pragma unroll
    for (int off = 32; off >= 1; off >>= 1) s += __shfl_xor(s, off);
    if (lane == 0) red[wave] = s;
    __syncthreads();
    float mu = (red[0] + red[1] + red[2] + red[3]) * (1.f / 1024.f);
    float d0 = x0 - mu, d1 = x1 - mu, d2 = x2 - mu, d3 = x3 - mu;
    float s2 = d0 * d0 + d1 * d1 + d2 * d2 + d3 * d3;
#pragma unroll
    for (int off = 32; off >= 1; off >>= 1) s2 += __shfl_xor(s2, off);
    if (lane == 0) red[4 + wave] = s2;
    __syncthreads();
    float var = (red[4] + red[5] + red[6] + red[7]) * (1.f / 1024.f);
    float rs = rsqrtf(var + 1e-6f);
    float4 gv = reinterpret_cast<const float4*>(g)[tid];
    float4 bv = reinterpret_cast<const float4*>(bt)[tid];
    float o0 = d0 * rs * gv.x + bv.x;
    float o1 = d1 * rs * gv.y + bv.y;
    float o2 = d2 * rs * gv.z + bv.z;
    float o3 = d3 * rs * gv.w + bv.w;
    if (outf) {
        float4 ov; ov.x = o0; ov.y = o1; ov.z = o2; ov.w = o3;
        reinterpret_cast<float4*>(outf + (size_t)row * 1024)[tid] = ov;
    }
    if (outb) {
        ushort4v ob; ob[0] = f2b(o0); ob[1] = f2b(o1); ob[2] = f2b(o2); ob[3] = f2b(o3);
        reinterpret_cast<ushort4v*>(outb + (size_t)row * 1024)[tid] = ob;
    }
}

extern "C" void kernel_launch(void* const* d_in, const int* in_sizes, int n_in,
                              void* d_out, int out_size, void* d_ws, size_t ws_size,
                              hipStream_t stream) {
    const float* x    = (const float*)d_in[0];
    const float* mask = (const float*)d_in[1];
    const float* wq   = (const float*)d_in[2];
    const float* wq_b = (const float*)d_in[3];
    const float* wk   = (const float*)d_in[4];
    const float* wk_b = (const float*)d_in[5];
    const float* wv   = (const float*)d_in[6];
    const float* wv_b = (const float*)d_in[7];
    const float* wo   = (const float*)d_in[8];
    const float* wo_b = (const float*)d_in[9];
    const float* w1   = (const float*)d_in[10];
    const float* b1   = (const float*)d_in[11];
    const float* w2   = (const float*)d_in[12];
    const float* b2   = (const float*)d_in[13];
    const float* ln1g = (const float*)d_in[14];
    const float* ln1b = (const float*)d_in[15];
    const float* ln2g = (const float*)d_in[16];
    const float* ln2b = (const float*)d_in[17];
    float* out = (float*)d_out;

    char* ws = (char*)d_ws;
    const size_t MB = 1024ull * 1024ull;
    u16*   qkv_b  = (u16*)(ws + 0);
    u16*   h_b    = (u16*)(ws + 0);
    u16*   vTb    = (u16*)(ws + 64 * MB);
    float* ybuf   = (float*)(ws + 64 * MB);
    float* po     = (float*)(ws + 96 * MB);
    float* ml     = (float*)(ws + 113 * MB);
    float* out1   = (float*)(ws + 96 * MB);
    u16*   xb     = (u16*)(ws + 128 * MB);
    u16*   attn_b = (u16*)(ws + 128 * MB);
    u16*   out1_b = (u16*)(ws + 128 * MB);
    u16*   wT     = (u16*)(ws + 144 * MB);
    float* bias3  = (float*)(ws + 152 * MB);

    const dim3 tb(256);
    const dim3 tg(512);

    // x -> bf16
    k_f32_to_bf16<<<(M_ * D_ / 4 + 255) / 256, tb, 0, stream>>>(x, xb, M_ * D_ / 4);
    // pack W_qkv^T bf16 [3072][1024] + bias
    k_transpose_bf16<<<dim3(32, 32), tb, 0, stream>>>(wq, wT, 1024, 1024, 0);
    k_transpose_bf16<<<dim3(32, 32), tb, 0, stream>>>(wk, wT, 1024, 1024, 1024);
    k_transpose_bf16<<<dim3(32, 32), tb, 0, stream>>>(wv, wT, 1024, 1024, 2048);
    k_pack_bias3<<<12, tb, 0, stream>>>(wq_b, wk_b, wv_b, bias3);
    // QKV: [8192,3072] bf16 — 256x256 tile
    k_gemm2<256, false, false, true><<<dim3(M_ / 256, 3072 / 256), tg, 0, stream>>>(
        xb, wT, bias3, nullptr, qkv_b, M_, 3072, 1024);
    // V pre-transpose for attention PV
    k_transpose_v<<<dim3(S_ / 32, 2, B_ * H_), tb, 0, stream>>>(qkv_b, vTb);
    // attention -> attn_b bf16 [B,S,H,64]
    k_attn_local<<<dim3(S_ / 64, HL_, B_), tb, 0, stream>>>(qkv_b, vTb, attn_b);
    k_attn_global_part<<<dim3(S_ / 64, HG_ * NCH_, B_), tb, 0, stream>>>(qkv_b, vTb, mask, po, ml);
    k_attn_merge<<<dim3(S_ / 64, HG_, B_), tb, 0, stream>>>(po, ml, attn_b);
    // output projection — 128x256 tile (grid 64x4 = 256 blocks)
    k_transpose_bf16<<<dim3(32, 32), tb, 0, stream>>>(wo, wT, 1024, 1024, 0);
    k_gemm2<128, false, true, false><<<dim3(M_ / 128, 1024 / 256), tg, 0, stream>>>(
        attn_b, wT, wo_b, ybuf, nullptr, M_, 1024, 1024);
    // LN1 (residual x)
    k_ln<<<M_, tb, 0, stream>>>(x, ybuf, ln1g, ln1b, out1, out1_b);
    // FFN1 (leaky relu 0.2) — 256x256 tile
    k_transpose_bf16<<<dim3(128, 32), tb, 0, stream>>>(w1, wT, 1024, 4096, 0);
    k_gemm2<256, true, false, true><<<dim3(M_ / 256, 4096 / 256), tg, 0, stream>>>(
        out1_b, wT, b1, nullptr, h_b, M_, 4096, 1024);
    // FFN2 — 128x256 tile
    k_transpose_bf16<<<dim3(32, 128), tb, 0, stream>>>(w2, wT, 4096, 1024, 0);
    k_gemm2<128, false, true, false><<<dim3(M_ / 128, 1024 / 256), tg, 0, stream>>>(
        h_b, wT, b2, ybuf, nullptr, M_, 1024, 4096);
    // LN2 (residual out1) -> final output f32
    k_ln<<<M_, tb, 0, stream>>>(out1, ybuf, ln2g, ln2b, out, nullptr);
}

// Round 10
// 386.612 us; speedup vs baseline: 1.1334x; 1.1334x over previous
//
#include <hip/hip_runtime.h>
#include <hip/hip_bf16.h>

typedef unsigned short u16;
typedef unsigned int u32;
typedef __attribute__((ext_vector_type(8))) short short8;
typedef __attribute__((ext_vector_type(8))) unsigned short ushort8v;
typedef __attribute__((ext_vector_type(4))) unsigned short ushort4v;
typedef __attribute__((ext_vector_type(4))) float f32x4;

static constexpr int B_ = 2, S_ = 4096, D_ = 1024, H_ = 16, HG_ = 2, W_ = 128, DFF_ = 4096;
static constexpr int HL_ = H_ - HG_;   // 14 local heads
static constexpr int M_ = B_ * S_;     // 8192 rows
static constexpr int NCH_ = 4;         // KV chunks for global-head split

static __device__ __forceinline__ u16 f2b(float f) {
    u32 u = __builtin_bit_cast(u32, f);
    u32 r = (u + 0x7fffu + ((u >> 16) & 1u)) >> 16;   // RNE
    return (u16)r;
}
static __device__ __forceinline__ float b2f(u16 b) {
    return __builtin_bit_cast(float, (u32)b << 16);
}

// ---------------- f32 -> bf16 convert (vectorized) ----------------
__global__ __launch_bounds__(256) void k_f32_to_bf16(const float* __restrict__ src,
                                                     u16* __restrict__ dst, int n4) {
    int i = blockIdx.x * 256 + threadIdx.x;
    if (i >= n4) return;
    float4 v = reinterpret_cast<const float4*>(src)[i];
    ushort4v o; o[0] = f2b(v.x); o[1] = f2b(v.y); o[2] = f2b(v.z); o[3] = f2b(v.w);
    reinterpret_cast<ushort4v*>(dst)[i] = o;
}

// ---------------- weight transpose+convert: W[K][N] f32 -> WT[ro+N][K] bf16 ----------------
__global__ __launch_bounds__(256) void k_transpose_bf16(const float* __restrict__ src,
                                                        u16* __restrict__ dst,
                                                        int K, int N, int ro) {
    __shared__ float tile[32][33];
    const int tx = threadIdx.x & 31, ty = threadIdx.x >> 5;  // 32x8
    const int bx = blockIdx.x, by = blockIdx.y;
#pragma unroll
    for (int jj = 0; jj < 4; ++jj) {
        int kk = by * 32 + ty + jj * 8;
        int nn = bx * 32 + tx;
        tile[ty + jj * 8][tx] = src[(size_t)kk * N + nn];
    }
    __syncthreads();
#pragma unroll
    for (int jj = 0; jj < 4; ++jj) {
        int nn = bx * 32 + ty + jj * 8;
        int kk = by * 32 + tx;
        dst[(size_t)(ro + nn) * K + kk] = f2b(tile[tx][ty + jj * 8]);
    }
}

// ---------------- V transpose: qkv V-cols -> vT[(b*H+h)*64 + d][S] bf16 ----------------
__global__ __launch_bounds__(256) void k_transpose_v(const u16* __restrict__ qkv,
                                                     u16* __restrict__ vT) {
    __shared__ u16 tile[32][33];
    const int tx = threadIdx.x & 31, ty = threadIdx.x >> 5;  // 32x8
    const int s0 = blockIdx.x * 32;
    const int d0 = blockIdx.y * 32;
    const int bh = blockIdx.z;
    const int b = bh >> 4, h = bh & 15;
#pragma unroll
    for (int jj = 0; jj < 4; ++jj) {
        int srow = s0 + ty + jj * 8;
        tile[ty + jj * 8][tx] = qkv[(size_t)(b * S_ + srow) * 3072 + 2048 + h * 64 + d0 + tx];
    }
    __syncthreads();
#pragma unroll
    for (int jj = 0; jj < 4; ++jj) {
        int d = d0 + ty + jj * 8;
        vT[(size_t)((b * H_ + h) * 64 + d) * S_ + s0 + tx] = tile[tx][ty + jj * 8];
    }
}

__global__ void k_pack_bias3(const float* __restrict__ a, const float* __restrict__ b,
                             const float* __restrict__ c, float* __restrict__ dst) {
    int i = blockIdx.x * 256 + threadIdx.x;
    if (i >= 3072) return;
    dst[i] = i < 1024 ? a[i] : (i < 2048 ? b[i - 1024] : c[i - 2048]);
}

#define GLDS16(gp, lp) __builtin_amdgcn_global_load_lds( \
    (const __attribute__((address_space(1))) void*)(gp),  \
    (__attribute__((address_space(3))) void*)(lp), 16, 0, 0)

// ---------------- bf16 MFMA GEMM, BK=64 single-buffer (FROZEN r8 config) ----------------
// 128x128 tile, 4 waves, 16x16x32 MFMA, 2-barrier loop, granule XOR swizzle both sides.
// Best measured: MfmaUtil 32%, conflicts 0. GEMM structure frozen after 7 variants
// (r3..r9) all landed 26-32%; r8 is the max.
template <bool LEAKY, bool OUTF, bool OUTB>
__global__ __launch_bounds__(256) void k_gemm(const u16* __restrict__ A, const u16* __restrict__ Bt,
                                              const float* __restrict__ bias,
                                              float* __restrict__ Cf, u16* __restrict__ Cb,
                                              int M, int N, int K) {
    __shared__ __align__(16) u16 lA[128 * 64];
    __shared__ __align__(16) u16 lB[128 * 64];
    const int tid = threadIdx.x;
    const int lane = tid & 63, wave = tid >> 6;
    const int wr = wave >> 1, wc = wave & 1;
    const int m0 = blockIdx.x * 128, n0 = blockIdx.y * 128;

    f32x4 acc[4][4];
#pragma unroll
    for (int i = 0; i < 4; ++i)
#pragma unroll
        for (int j = 0; j < 4; ++j)
#pragma unroll
            for (int e = 0; e < 4; ++e) acc[i][j][e] = 0.f;

    const int srow = tid >> 3;                  // 0..31
    const int sgc = (tid & 7) ^ (srow & 7);     // inverse-swizzled source granule
    const int c = lane & 15, g4 = lane >> 4;

    const u16* gA = A + (size_t)(m0 + srow) * K + sgc * 8;
    const u16* gB = Bt + (size_t)(n0 + srow) * K + sgc * 8;

    const char* lAc = reinterpret_cast<const char*>(lA);
    const char* lBc = reinterpret_cast<const char*>(lB);

    for (int k0 = 0; k0 < K; k0 += 64) {
        __syncthreads();
#pragma unroll
        for (int j = 0; j < 4; ++j) {
            GLDS16(gA + k0 + (size_t)j * 32 * K, lA + j * 2048 + wave * 512);
            GLDS16(gB + k0 + (size_t)j * 32 * K, lB + j * 2048 + wave * 512);
        }
        __syncthreads();

#pragma unroll
        for (int ks = 0; ks < 2; ++ks) {
            short8 af[4], bfr[4];
#pragma unroll
            for (int mi = 0; mi < 4; ++mi) {
                const int r = wr * 64 + mi * 16 + c;
                const int gl = (ks * 4 + g4) ^ (c & 7);
                af[mi] = *reinterpret_cast<const short8*>(lAc + r * 128 + gl * 16);
            }
#pragma unroll
            for (int ni = 0; ni < 4; ++ni) {
                const int r = wc * 64 + ni * 16 + c;
                const int gl = (ks * 4 + g4) ^ (c & 7);
                bfr[ni] = *reinterpret_cast<const short8*>(lBc + r * 128 + gl * 16);
            }
            __builtin_amdgcn_s_setprio(1);
#pragma unroll
            for (int mi = 0; mi < 4; ++mi)
#pragma unroll
                for (int ni = 0; ni < 4; ++ni)
                    acc[mi][ni] = __builtin_amdgcn_mfma_f32_16x16x32_bf16(af[mi], bfr[ni], acc[mi][ni], 0, 0, 0);
            __builtin_amdgcn_s_setprio(0);
        }
    }

#pragma unroll
    for (int mi = 0; mi < 4; ++mi) {
        const int rowb = m0 + wr * 64 + mi * 16 + (lane >> 4) * 4;
#pragma unroll
        for (int ni = 0; ni < 4; ++ni) {
            const int col = n0 + wc * 64 + ni * 16 + (lane & 15);
            const float bs = bias[col];
#pragma unroll
            for (int j = 0; j < 4; ++j) {
                float v = acc[mi][ni][j] + bs;
                if (LEAKY) v = v > 0.f ? v : 0.2f * v;
                const size_t idx = (size_t)(rowb + j) * N + col;
                if (OUTF) Cf[idx] = v;
                if (OUTB) Cb[idx] = f2b(v);
            }
        }
    }
}

// ---------------- MFMA flash attention, LOCAL (banded) heads ----------------
__global__ __launch_bounds__(256) void k_attn_local(const u16* __restrict__ qkv,
                                                    const u16* __restrict__ vT,
                                                    u16* __restrict__ out) {
    __shared__ __align__(16) u16 Kl[64][72];
    __shared__ __align__(16) u16 Vl[64][72];
    __shared__ __align__(16) u16 Pl[4][1024];
    const int tid = threadIdx.x, lane = tid & 63, wave = tid >> 6;
    const int c = lane & 15, g = lane >> 4;
    const int b = blockIdx.z, h = blockIdx.y;
    const int q0 = blockIdx.x * 64;
    const int qrow = q0 + wave * 16 + c;

    short8 qf[2];
    {
        const u16* qp = qkv + (size_t)(b * S_ + qrow) * 3072 + h * 64 + g * 8;
        qf[0] = *reinterpret_cast<const short8*>(qp);
        qf[1] = *reinterpret_cast<const short8*>(qp + 32);
    }

    f32x4 acc[4];
#pragma unroll
    for (int dt = 0; dt < 4; ++dt)
#pragma unroll
        for (int j = 0; j < 4; ++j) acc[dt][j] = 0.f;
    float mrow = -1e30f, lrow = 0.f;

    const int t_lo = max(0, q0 - W_) >> 6;
    const int t_hi = min(S_ - 1, q0 + 63 + W_) >> 6;
    u16* pw = Pl[wave];

    for (int t = t_lo; t <= t_hi; ++t) {
        __syncthreads();
#pragma unroll
        for (int it = 0; it < 2; ++it) {
            int L = it * 256 + tid;
            int r = L >> 3, cb = (L & 7) * 8;
            *reinterpret_cast<ushort8v*>(&Kl[r][cb]) =
                *reinterpret_cast<const ushort8v*>(&qkv[(size_t)(b * S_ + t * 64 + r) * 3072 + 1024 + h * 64 + cb]);
            *reinterpret_cast<ushort8v*>(&Vl[r][cb]) =
                *reinterpret_cast<const ushort8v*>(&vT[(size_t)((b * H_ + h) * 64 + r) * S_ + t * 64 + cb]);
        }
        __syncthreads();

        f32x4 s[4];
#pragma unroll
        for (int nt = 0; nt < 4; ++nt)
#pragma unroll
            for (int j = 0; j < 4; ++j) s[nt][j] = 0.f;
        __builtin_amdgcn_s_setprio(1);
#pragma unroll
        for (int kc = 0; kc < 2; ++kc) {
#pragma unroll
            for (int nt = 0; nt < 4; ++nt) {
                short8 kf = *reinterpret_cast<const short8*>(&Kl[nt * 16 + c][kc * 32 + g * 8]);
                s[nt] = __builtin_amdgcn_mfma_f32_16x16x32_bf16(kf, qf[kc], s[nt], 0, 0, 0);
            }
        }
        __builtin_amdgcn_s_setprio(0);

        float p[4][4];
        float tmax = -1e30f;
#pragma unroll
        for (int nt = 0; nt < 4; ++nt)
#pragma unroll
            for (int j = 0; j < 4; ++j) {
                float sv = s[nt][j] * 0.125f;
                int key = t * 64 + nt * 16 + 4 * g + j;
                bool val = (key >= qrow - W_) && (key <= qrow + W_);
                sv = val ? sv : -1e30f;
                p[nt][j] = sv;
                tmax = fmaxf(tmax, sv);
            }
        tmax = fmaxf(tmax, __shfl_xor(tmax, 16));
        tmax = fmaxf(tmax, __shfl_xor(tmax, 32));
        float mnew = fmaxf(mrow, tmax);
        float fac = __expf(mrow - mnew);
        mrow = mnew;
        float psum = 0.f;
#pragma unroll
        for (int nt = 0; nt < 4; ++nt)
#pragma unroll
            for (int j = 0; j < 4; ++j) {
                p[nt][j] = __expf(p[nt][j] - mnew);
                psum += p[nt][j];
            }
        lrow = lrow * fac + psum;
#pragma unroll
        for (int dt = 0; dt < 4; ++dt)
#pragma unroll
            for (int j = 0; j < 4; ++j) acc[dt][j] *= fac;

#pragma unroll
        for (int nt = 0; nt < 4; ++nt)
#pragma unroll
            for (int jp = 0; jp < 2; ++jp) {
                u32 pk = (u32)f2b(p[nt][2 * jp]) | ((u32)f2b(p[nt][2 * jp + 1]) << 16);
                int byteoff = (c << 7) + ((nt * 32 + 8 * g + 4 * jp) ^ ((c & 7) << 4));
                *reinterpret_cast<u32*>(reinterpret_cast<char*>(pw) + byteoff) = pk;
            }
        asm volatile("s_waitcnt lgkmcnt(0)" ::: "memory");

        __builtin_amdgcn_s_setprio(1);
#pragma unroll
        for (int h2 = 0; h2 < 2; ++h2) {
            int rb = (c << 7) + ((h2 * 64 + g * 16) ^ ((c & 7) << 4));
            short8 pa = *reinterpret_cast<const short8*>(reinterpret_cast<char*>(pw) + rb);
#pragma unroll
            for (int dt = 0; dt < 4; ++dt) {
                short8 vf = *reinterpret_cast<const short8*>(&Vl[dt * 16 + c][h2 * 32 + g * 8]);
                acc[dt] = __builtin_amdgcn_mfma_f32_16x16x32_bf16(vf, pa, acc[dt], 0, 0, 0);
            }
        }
        __builtin_amdgcn_s_setprio(0);
    }

    float lfull = lrow + __shfl_xor(lrow, 16);
    lfull += __shfl_xor(lfull, 32);
    const float rinv = 1.0f / lfull;

#pragma unroll
    for (int dt = 0; dt < 4; ++dt) {
        u32 w0 = (u32)f2b(acc[dt][0] * rinv) | ((u32)f2b(acc[dt][1] * rinv) << 16);
        u32 w1 = (u32)f2b(acc[dt][2] * rinv) | ((u32)f2b(acc[dt][3] * rinv) << 16);
        uint2 wv; wv.x = w0; wv.y = w1;
        *reinterpret_cast<uint2*>(out + (size_t)(b * S_ + qrow) * 1024 + h * 64 + dt * 16 + 4 * g) = wv;
    }
}

// ---------------- GLOBAL heads: split-KV partial flash ----------------
__global__ __launch_bounds__(256) void k_attn_global_part(const u16* __restrict__ qkv,
                                                          const u16* __restrict__ vT,
                                                          const float* __restrict__ mask,
                                                          float* __restrict__ po,
                                                          float* __restrict__ ml) {
    __shared__ __align__(16) u16 Kl[64][72];
    __shared__ __align__(16) u16 Vl[64][72];
    __shared__ __align__(16) u16 Pl[4][1024];
    __shared__ float maskl[64];
    const int tid = threadIdx.x, lane = tid & 63, wave = tid >> 6;
    const int c = lane & 15, g = lane >> 4;
    const int b = blockIdx.z;
    const int hh = blockIdx.y >> 2, ch = blockIdx.y & 3;
    const int h = HL_ + hh;
    const int q0 = blockIdx.x * 64;
    const int qrow = q0 + wave * 16 + c;

    short8 qf[2];
    {
        const u16* qp = qkv + (size_t)(b * S_ + qrow) * 3072 + h * 64 + g * 8;
        qf[0] = *reinterpret_cast<const short8*>(qp);
        qf[1] = *reinterpret_cast<const short8*>(qp + 32);
    }

    f32x4 acc[4];
#pragma unroll
    for (int dt = 0; dt < 4; ++dt)
#pragma unroll
        for (int j = 0; j < 4; ++j) acc[dt][j] = 0.f;
    float mrow = -1e30f, lrow = 0.f;
    u16* pw = Pl[wave];

    const int t_lo = ch * (S_ / 64 / NCH_), t_hi = t_lo + (S_ / 64 / NCH_) - 1;
    for (int t = t_lo; t <= t_hi; ++t) {
        __syncthreads();
#pragma unroll
        for (int it = 0; it < 2; ++it) {
            int L = it * 256 + tid;
            int r = L >> 3, cb = (L & 7) * 8;
            *reinterpret_cast<ushort8v*>(&Kl[r][cb]) =
                *reinterpret_cast<const ushort8v*>(&qkv[(size_t)(b * S_ + t * 64 + r) * 3072 + 1024 + h * 64 + cb]);
            *reinterpret_cast<ushort8v*>(&Vl[r][cb]) =
                *reinterpret_cast<const ushort8v*>(&vT[(size_t)((b * H_ + h) * 64 + r) * S_ + t * 64 + cb]);
        }
        if (tid < 64) maskl[tid] = mask[b * S_ + t * 64 + tid] * (-1000.0f);
        __syncthreads();

        f32x4 s[4];
#pragma unroll
        for (int nt = 0; nt < 4; ++nt)
#pragma unroll
            for (int j = 0; j < 4; ++j) s[nt][j] = 0.f;
        __builtin_amdgcn_s_setprio(1);
#pragma unroll
        for (int kc = 0; kc < 2; ++kc) {
#pragma unroll
            for (int nt = 0; nt < 4; ++nt) {
                short8 kf = *reinterpret_cast<const short8*>(&Kl[nt * 16 + c][kc * 32 + g * 8]);
                s[nt] = __builtin_amdgcn_mfma_f32_16x16x32_bf16(kf, qf[kc], s[nt], 0, 0, 0);
            }
        }
        __builtin_amdgcn_s_setprio(0);

        float p[4][4];
        float tmax = -1e30f;
#pragma unroll
        for (int nt = 0; nt < 4; ++nt)
#pragma unroll
            for (int j = 0; j < 4; ++j) {
                float sv = s[nt][j] * 0.125f + maskl[nt * 16 + 4 * g + j];
                p[nt][j] = sv;
                tmax = fmaxf(tmax, sv);
            }
        tmax = fmaxf(tmax, __shfl_xor(tmax, 16));
        tmax = fmaxf(tmax, __shfl_xor(tmax, 32));
        float mnew = fmaxf(mrow, tmax);
        float fac = __expf(mrow - mnew);
        mrow = mnew;
        float psum = 0.f;
#pragma unroll
        for (int nt = 0; nt < 4; ++nt)
#pragma unroll
            for (int j = 0; j < 4; ++j) {
                p[nt][j] = __expf(p[nt][j] - mnew);
                psum += p[nt][j];
            }
        lrow = lrow * fac + psum;
#pragma unroll
        for (int dt = 0; dt < 4; ++dt)
#pragma unroll
            for (int j = 0; j < 4; ++j) acc[dt][j] *= fac;

#pragma unroll
        for (int nt = 0; nt < 4; ++nt)
#pragma unroll
            for (int jp = 0; jp < 2; ++jp) {
                u32 pk = (u32)f2b(p[nt][2 * jp]) | ((u32)f2b(p[nt][2 * jp + 1]) << 16);
                int byteoff = (c << 7) + ((nt * 32 + 8 * g + 4 * jp) ^ ((c & 7) << 4));
                *reinterpret_cast<u32*>(reinterpret_cast<char*>(pw) + byteoff) = pk;
            }
        asm volatile("s_waitcnt lgkmcnt(0)" ::: "memory");

        __builtin_amdgcn_s_setprio(1);
#pragma unroll
        for (int h2 = 0; h2 < 2; ++h2) {
            int rb = (c << 7) + ((h2 * 64 + g * 16) ^ ((c & 7) << 4));
            short8 pa = *reinterpret_cast<const short8*>(reinterpret_cast<char*>(pw) + rb);
#pragma unroll
            for (int dt = 0; dt < 4; ++dt) {
                short8 vf = *reinterpret_cast<const short8*>(&Vl[dt * 16 + c][h2 * 32 + g * 8]);
                acc[dt] = __builtin_amdgcn_mfma_f32_16x16x32_bf16(vf, pa, acc[dt], 0, 0, 0);
            }
        }
        __builtin_amdgcn_s_setprio(0);
    }

    float lfull = lrow + __shfl_xor(lrow, 16);
    lfull += __shfl_xor(lfull, 32);

    float* po_blk = po + ((((size_t)(b * HG_ + hh) * NCH_ + ch) * (S_ / 64) + blockIdx.x) * 4096);
    const int ql = wave * 16 + c;
#pragma unroll
    for (int dt = 0; dt < 4; ++dt)
        *reinterpret_cast<f32x4*>(po_blk + ql * 64 + dt * 16 + 4 * g) = acc[dt];
    if (g == 0) {
        size_t mb = (((size_t)(b * HG_ + hh) * NCH_ + ch) * S_ + q0 + ql) * 2;
        ml[mb] = mrow;
        ml[mb + 1] = lfull;
    }
}

// ---------------- merge split-KV partials -> bf16 attn output ----------------
__global__ __launch_bounds__(256) void k_attn_merge(const float* __restrict__ po,
                                                    const float* __restrict__ ml,
                                                    u16* __restrict__ out) {
    const int qb = blockIdx.x, hh = blockIdx.y, b = blockIdx.z;
    const int t = threadIdx.x;
    const int ql = t >> 2, d0 = (t & 3) * 16;
    const int q = qb * 64 + ql;

    float mv[NCH_], lv[NCH_];
    float M = -1e30f;
#pragma unroll
    for (int ch = 0; ch < NCH_; ++ch) {
        size_t mb = (((size_t)(b * HG_ + hh) * NCH_ + ch) * S_ + q) * 2;
        mv[ch] = ml[mb];
        lv[ch] = ml[mb + 1];
        M = fmaxf(M, mv[ch]);
    }
    float wch[NCH_], L = 0.f;
#pragma unroll
    for (int ch = 0; ch < NCH_; ++ch) {
        wch[ch] = __expf(mv[ch] - M);
        L += wch[ch] * lv[ch];
    }
    const float rL = 1.0f / L;

    float o[16];
#pragma unroll
    for (int i = 0; i < 16; ++i) o[i] = 0.f;
#pragma unroll
    for (int ch = 0; ch < NCH_; ++ch) {
        const float* pb = po + ((((size_t)(b * HG_ + hh) * NCH_ + ch) * (S_ / 64) + qb) * 4096) + ql * 64 + d0;
        const float w = wch[ch];
#pragma unroll
        for (int i = 0; i < 4; ++i) {
            float4 v = reinterpret_cast<const float4*>(pb)[i];
            o[4 * i + 0] += w * v.x; o[4 * i + 1] += w * v.y;
            o[4 * i + 2] += w * v.z; o[4 * i + 3] += w * v.w;
        }
    }
    ushort8v r0, r1;
#pragma unroll
    for (int i = 0; i < 8; ++i) { r0[i] = f2b(o[i] * rL); r1[i] = f2b(o[8 + i] * rL); }
    u16* op = out + (size_t)(b * S_ + q) * 1024 + (HL_ + hh) * 64 + d0;
    *reinterpret_cast<ushort8v*>(op) = r0;
    *reinterpret_cast<ushort8v*>(op + 8) = r1;
}

// ---------------- fused residual + LayerNorm (row = 1024), bf16 delta/base paths ----------------
// BASEF: base is f32 (else bf16). Delta always bf16. Outputs: optional f32, optional bf16.
template <bool BASEF>
__global__ __launch_bounds__(256) void k_ln(const float* __restrict__ basef, const u16* __restrict__ baseb,
                                            const u16* __restrict__ delta,
                                            const float* __restrict__ g, const float* __restrict__ bt,
                                            float* __restrict__ outf, u16* __restrict__ outb) {
    __shared__ float red[8];
    const int row = blockIdx.x, tid = threadIdx.x;
    const int lane = tid & 63, wave = tid >> 6;
    float x0, x1, x2, x3;
    if (BASEF) {
        float4 xb = reinterpret_cast<const float4*>(basef + (size_t)row * 1024)[tid];
        x0 = xb.x; x1 = xb.y; x2 = xb.z; x3 = xb.w;
    } else {
        ushort4v xb = reinterpret_cast<const ushort4v*>(baseb + (size_t)row * 1024)[tid];
        x0 = b2f(xb[0]); x1 = b2f(xb[1]); x2 = b2f(xb[2]); x3 = b2f(xb[3]);
    }
    ushort4v xd = reinterpret_cast<const ushort4v*>(delta + (size_t)row * 1024)[tid];
    x0 += b2f(xd[0]); x1 += b2f(xd[1]); x2 += b2f(xd[2]); x3 += b2f(xd[3]);
    float s = x0 + x1 + x2 + x3;
#pragma unroll
    for (int off = 32; off >= 1; off >>= 1) s += __shfl_xor(s, off);
    if (lane == 0) red[wave] = s;
    __syncthreads();
    float mu = (red[0] + red[1] + red[2] + red[3]) * (1.f / 1024.f);
    float d0 = x0 - mu, d1 = x1 - mu, d2 = x2 - mu, d3 = x3 - mu;
    float s2 = d0 * d0 + d1 * d1 + d2 * d2 + d3 * d3;
#pragma unroll
    for (int off = 32; off >= 1; off >>= 1) s2 += __shfl_xor(s2, off);
    if (lane == 0) red[4 + wave] = s2;
    __syncthreads();
    float var = (red[4] + red[5] + red[6] + red[7]) * (1.f / 1024.f);
    float rs = rsqrtf(var + 1e-6f);
    float4 gv = reinterpret_cast<const float4*>(g)[tid];
    float4 bv = reinterpret_cast<const float4*>(bt)[tid];
    float o0 = d0 * rs * gv.x + bv.x;
    float o1 = d1 * rs * gv.y + bv.y;
    float o2 = d2 * rs * gv.z + bv.z;
    float o3 = d3 * rs * gv.w + bv.w;
    if (outf) {
        float4 ov; ov.x = o0; ov.y = o1; ov.z = o2; ov.w = o3;
        reinterpret_cast<float4*>(outf + (size_t)row * 1024)[tid] = ov;
    }
    if (outb) {
        ushort4v ob; ob[0] = f2b(o0); ob[1] = f2b(o1); ob[2] = f2b(o2); ob[3] = f2b(o3);
        reinterpret_cast<ushort4v*>(outb + (size_t)row * 1024)[tid] = ob;
    }
}

extern "C" void kernel_launch(void* const* d_in, const int* in_sizes, int n_in,
                              void* d_out, int out_size, void* d_ws, size_t ws_size,
                              hipStream_t stream) {
    const float* x    = (const float*)d_in[0];
    const float* mask = (const float*)d_in[1];
    const float* wq   = (const float*)d_in[2];
    const float* wq_b = (const float*)d_in[3];
    const float* wk   = (const float*)d_in[4];
    const float* wk_b = (const float*)d_in[5];
    const float* wv   = (const float*)d_in[6];
    const float* wv_b = (const float*)d_in[7];
    const float* wo   = (const float*)d_in[8];
    const float* wo_b = (const float*)d_in[9];
    const float* w1   = (const float*)d_in[10];
    const float* b1   = (const float*)d_in[11];
    const float* w2   = (const float*)d_in[12];
    const float* b2   = (const float*)d_in[13];
    const float* ln1g = (const float*)d_in[14];
    const float* ln1b = (const float*)d_in[15];
    const float* ln2g = (const float*)d_in[16];
    const float* ln2b = (const float*)d_in[17];
    float* out = (float*)d_out;

    char* ws = (char*)d_ws;
    const size_t MB = 1024ull * 1024ull;
    // [0,64MB): qkv bf16 (48MB) -> FFN hidden bf16 (64MB)
    u16*   qkv_b  = (u16*)(ws + 0);
    u16*   h_b    = (u16*)(ws + 0);
    // [64,96MB): vT bf16 (32MB, attn phase) -> WO-out bf16 (16MB) -> FFN2-out bf16 (16MB)
    u16*   vTb    = (u16*)(ws + 64 * MB);
    u16*   ybuf_b = (u16*)(ws + 64 * MB);
    u16*   ffn2_b = (u16*)(ws + 64 * MB);
    // [96,128MB): global-attn partials (attn phase only)
    float* po     = (float*)(ws + 96 * MB);
    float* ml     = (float*)(ws + 113 * MB);
    // [128,144MB): x bf16 -> attn bf16 -> out1 bf16 (sequential; out1_b lives to LN2)
    u16*   xb     = (u16*)(ws + 128 * MB);
    u16*   attn_b = (u16*)(ws + 128 * MB);
    u16*   out1_b = (u16*)(ws + 128 * MB);
    // [144,152MB): transposed weights bf16 (max 8MB), sequential
    u16*   wT     = (u16*)(ws + 144 * MB);
    // [152MB,+12KB): packed qkv bias f32
    float* bias3  = (float*)(ws + 152 * MB);

    const dim3 tb(256);

    // x -> bf16
    k_f32_to_bf16<<<(M_ * D_ / 4 + 255) / 256, tb, 0, stream>>>(x, xb, M_ * D_ / 4);
    // pack W_qkv^T bf16 [3072][1024] + bias
    k_transpose_bf16<<<dim3(32, 32), tb, 0, stream>>>(wq, wT, 1024, 1024, 0);
    k_transpose_bf16<<<dim3(32, 32), tb, 0, stream>>>(wk, wT, 1024, 1024, 1024);
    k_transpose_bf16<<<dim3(32, 32), tb, 0, stream>>>(wv, wT, 1024, 1024, 2048);
    k_pack_bias3<<<12, tb, 0, stream>>>(wq_b, wk_b, wv_b, bias3);
    // QKV: [8192,3072] bf16
    k_gemm<false, false, true><<<dim3(M_ / 128, 3072 / 128), tb, 0, stream>>>(
        xb, wT, bias3, nullptr, qkv_b, M_, 3072, 1024);
    // V pre-transpose for attention PV
    k_transpose_v<<<dim3(S_ / 32, 2, B_ * H_), tb, 0, stream>>>(qkv_b, vTb);
    // attention -> attn_b bf16 [B,S,H,64]
    k_attn_local<<<dim3(S_ / 64, HL_, B_), tb, 0, stream>>>(qkv_b, vTb, attn_b);
    k_attn_global_part<<<dim3(S_ / 64, HG_ * NCH_, B_), tb, 0, stream>>>(qkv_b, vTb, mask, po, ml);
    k_attn_merge<<<dim3(S_ / 64, HG_, B_), tb, 0, stream>>>(po, ml, attn_b);
    // output projection -> bf16 delta
    k_transpose_bf16<<<dim3(32, 32), tb, 0, stream>>>(wo, wT, 1024, 1024, 0);
    k_gemm<false, false, true><<<dim3(M_ / 128, 1024 / 128), tb, 0, stream>>>(
        attn_b, wT, wo_b, nullptr, ybuf_b, M_, 1024, 1024);
    // LN1 (residual x f32 + bf16 delta) -> out1 bf16 only
    k_ln<true><<<M_, tb, 0, stream>>>(x, nullptr, ybuf_b, ln1g, ln1b, nullptr, out1_b);
    // FFN1 (leaky relu 0.2) -> h bf16
    k_transpose_bf16<<<dim3(128, 32), tb, 0, stream>>>(w1, wT, 1024, 4096, 0);
    k_gemm<true, false, true><<<dim3(M_ / 128, 4096 / 128), tb, 0, stream>>>(
        out1_b, wT, b1, nullptr, h_b, M_, 4096, 1024);
    // FFN2 -> bf16 delta
    k_transpose_bf16<<<dim3(32, 128), tb, 0, stream>>>(w2, wT, 4096, 1024, 0);
    k_gemm<false, false, true><<<dim3(M_ / 128, 1024 / 128), tb, 0, stream>>>(
        h_b, wT, b2, nullptr, ffn2_b, M_, 1024, 4096);
    // LN2 (residual out1 bf16 + bf16 delta) -> final output f32
    k_ln<false><<<M_, tb, 0, stream>>>(nullptr, out1_b, ffn2_b, ln2g, ln2b, out, nullptr);
}

// Round 11
// 374.527 us; speedup vs baseline: 1.1700x; 1.0323x over previous
//
#include <hip/hip_runtime.h>
#include <hip/hip_bf16.h>

typedef unsigned short u16;
typedef unsigned int u32;
typedef __attribute__((ext_vector_type(8))) short short8;
typedef __attribute__((ext_vector_type(8))) unsigned short ushort8v;
typedef __attribute__((ext_vector_type(4))) unsigned short ushort4v;
typedef __attribute__((ext_vector_type(4))) float f32x4;

static constexpr int B_ = 2, S_ = 4096, D_ = 1024, H_ = 16, HG_ = 2, W_ = 128, DFF_ = 4096;
static constexpr int HL_ = H_ - HG_;   // 14 local heads
static constexpr int M_ = B_ * S_;     // 8192 rows
static constexpr int NCH_ = 4;         // KV chunks for global-head split

static __device__ __forceinline__ u16 f2b(float f) {
    u32 u = __builtin_bit_cast(u32, f);
    u32 r = (u + 0x7fffu + ((u >> 16) & 1u)) >> 16;   // RNE
    return (u16)r;
}
static __device__ __forceinline__ float b2f(u16 b) {
    return __builtin_bit_cast(float, (u32)b << 16);
}

// ---------------- f32 -> bf16 convert (vectorized) ----------------
__global__ __launch_bounds__(256) void k_f32_to_bf16(const float* __restrict__ src,
                                                     u16* __restrict__ dst, int n4) {
    int i = blockIdx.x * 256 + threadIdx.x;
    if (i >= n4) return;
    float4 v = reinterpret_cast<const float4*>(src)[i];
    ushort4v o; o[0] = f2b(v.x); o[1] = f2b(v.y); o[2] = f2b(v.z); o[3] = f2b(v.w);
    reinterpret_cast<ushort4v*>(dst)[i] = o;
}

// ---------------- weight transpose+convert: W[K][N] f32 -> WT[ro+N][K] bf16 ----------------
__global__ __launch_bounds__(256) void k_transpose_bf16(const float* __restrict__ src,
                                                        u16* __restrict__ dst,
                                                        int K, int N, int ro) {
    __shared__ float tile[32][33];
    const int tx = threadIdx.x & 31, ty = threadIdx.x >> 5;  // 32x8
    const int bx = blockIdx.x, by = blockIdx.y;
#pragma unroll
    for (int jj = 0; jj < 4; ++jj) {
        int kk = by * 32 + ty + jj * 8;
        int nn = bx * 32 + tx;
        tile[ty + jj * 8][tx] = src[(size_t)kk * N + nn];
    }
    __syncthreads();
#pragma unroll
    for (int jj = 0; jj < 4; ++jj) {
        int nn = bx * 32 + ty + jj * 8;
        int kk = by * 32 + tx;
        dst[(size_t)(ro + nn) * K + kk] = f2b(tile[tx][ty + jj * 8]);
    }
}

// ---------------- fused 3-way 1024x1024 transpose (wq,wk,wv -> one WT) ----------------
__global__ __launch_bounds__(256) void k_transpose3(const float* __restrict__ a,
                                                    const float* __restrict__ b,
                                                    const float* __restrict__ c,
                                                    u16* __restrict__ dst) {
    __shared__ float tile[32][33];
    const float* src = blockIdx.z == 0 ? a : (blockIdx.z == 1 ? b : c);
    const int ro = blockIdx.z * 1024;
    const int tx = threadIdx.x & 31, ty = threadIdx.x >> 5;
    const int bx = blockIdx.x, by = blockIdx.y;
#pragma unroll
    for (int jj = 0; jj < 4; ++jj) {
        int kk = by * 32 + ty + jj * 8;
        int nn = bx * 32 + tx;
        tile[ty + jj * 8][tx] = src[(size_t)kk * 1024 + nn];
    }
    __syncthreads();
#pragma unroll
    for (int jj = 0; jj < 4; ++jj) {
        int nn = bx * 32 + ty + jj * 8;
        int kk = by * 32 + tx;
        dst[(size_t)(ro + nn) * 1024 + kk] = f2b(tile[tx][ty + jj * 8]);
    }
}

// ---------------- V transpose: qkv V-cols -> vT[(b*H+h)*64 + d][S] bf16 ----------------
__global__ __launch_bounds__(256) void k_transpose_v(const u16* __restrict__ qkv,
                                                     u16* __restrict__ vT) {
    __shared__ u16 tile[32][33];
    const int tx = threadIdx.x & 31, ty = threadIdx.x >> 5;  // 32x8
    const int s0 = blockIdx.x * 32;
    const int d0 = blockIdx.y * 32;
    const int bh = blockIdx.z;
    const int b = bh >> 4, h = bh & 15;
#pragma unroll
    for (int jj = 0; jj < 4; ++jj) {
        int srow = s0 + ty + jj * 8;
        tile[ty + jj * 8][tx] = qkv[(size_t)(b * S_ + srow) * 3072 + 2048 + h * 64 + d0 + tx];
    }
    __syncthreads();
#pragma unroll
    for (int jj = 0; jj < 4; ++jj) {
        int d = d0 + ty + jj * 8;
        vT[(size_t)((b * H_ + h) * 64 + d) * S_ + s0 + tx] = tile[tx][ty + jj * 8];
    }
}

__global__ void k_pack_bias3(const float* __restrict__ a, const float* __restrict__ b,
                             const float* __restrict__ c, float* __restrict__ dst) {
    int i = blockIdx.x * 256 + threadIdx.x;
    if (i >= 3072) return;
    dst[i] = i < 1024 ? a[i] : (i < 2048 ? b[i - 1024] : c[i - 2048]);
}

#define GLDS16(gp, lp) __builtin_amdgcn_global_load_lds( \
    (const __attribute__((address_space(1))) void*)(gp),  \
    (__attribute__((address_space(3))) void*)(lp), 16, 0, 0)

// ---------------- bf16 MFMA GEMM, BK=64 single-buffer (FROZEN r8 config) ----------------
template <bool LEAKY, bool OUTF, bool OUTB>
__global__ __launch_bounds__(256) void k_gemm(const u16* __restrict__ A, const u16* __restrict__ Bt,
                                              const float* __restrict__ bias,
                                              float* __restrict__ Cf, u16* __restrict__ Cb,
                                              int M, int N, int K) {
    __shared__ __align__(16) u16 lA[128 * 64];
    __shared__ __align__(16) u16 lB[128 * 64];
    const int tid = threadIdx.x;
    const int lane = tid & 63, wave = tid >> 6;
    const int wr = wave >> 1, wc = wave & 1;
    const int m0 = blockIdx.x * 128, n0 = blockIdx.y * 128;

    f32x4 acc[4][4];
#pragma unroll
    for (int i = 0; i < 4; ++i)
#pragma unroll
        for (int j = 0; j < 4; ++j)
#pragma unroll
            for (int e = 0; e < 4; ++e) acc[i][j][e] = 0.f;

    const int srow = tid >> 3;
    const int sgc = (tid & 7) ^ (srow & 7);
    const int c = lane & 15, g4 = lane >> 4;

    const u16* gA = A + (size_t)(m0 + srow) * K + sgc * 8;
    const u16* gB = Bt + (size_t)(n0 + srow) * K + sgc * 8;

    const char* lAc = reinterpret_cast<const char*>(lA);
    const char* lBc = reinterpret_cast<const char*>(lB);

    for (int k0 = 0; k0 < K; k0 += 64) {
        __syncthreads();
#pragma unroll
        for (int j = 0; j < 4; ++j) {
            GLDS16(gA + k0 + (size_t)j * 32 * K, lA + j * 2048 + wave * 512);
            GLDS16(gB + k0 + (size_t)j * 32 * K, lB + j * 2048 + wave * 512);
        }
        __syncthreads();

#pragma unroll
        for (int ks = 0; ks < 2; ++ks) {
            short8 af[4], bfr[4];
#pragma unroll
            for (int mi = 0; mi < 4; ++mi) {
                const int r = wr * 64 + mi * 16 + c;
                const int gl = (ks * 4 + g4) ^ (c & 7);
                af[mi] = *reinterpret_cast<const short8*>(lAc + r * 128 + gl * 16);
            }
#pragma unroll
            for (int ni = 0; ni < 4; ++ni) {
                const int r = wc * 64 + ni * 16 + c;
                const int gl = (ks * 4 + g4) ^ (c & 7);
                bfr[ni] = *reinterpret_cast<const short8*>(lBc + r * 128 + gl * 16);
            }
            __builtin_amdgcn_s_setprio(1);
#pragma unroll
            for (int mi = 0; mi < 4; ++mi)
#pragma unroll
                for (int ni = 0; ni < 4; ++ni)
                    acc[mi][ni] = __builtin_amdgcn_mfma_f32_16x16x32_bf16(af[mi], bfr[ni], acc[mi][ni], 0, 0, 0);
            __builtin_amdgcn_s_setprio(0);
        }
    }

#pragma unroll
    for (int mi = 0; mi < 4; ++mi) {
        const int rowb = m0 + wr * 64 + mi * 16 + (lane >> 4) * 4;
#pragma unroll
        for (int ni = 0; ni < 4; ++ni) {
            const int col = n0 + wc * 64 + ni * 16 + (lane & 15);
            const float bs = bias[col];
#pragma unroll
            for (int j = 0; j < 4; ++j) {
                float v = acc[mi][ni][j] + bs;
                if (LEAKY) v = v > 0.f ? v : 0.2f * v;
                const size_t idx = (size_t)(rowb + j) * N + col;
                if (OUTF) Cf[idx] = v;
                if (OUTB) Cb[idx] = f2b(v);
            }
        }
    }
}

// ---------------- MFMA flash attention, LOCAL (banded) heads ----------------
// T14 async-stage: tile t+1 global loads issued into regs before tile t compute.
// XCD swizzle: bijective 3-bit rotate on q-block id -> each XCD owns a contiguous
// q band per (h,b) -> contiguous KV reuse in its private L2.
__global__ __launch_bounds__(256) void k_attn_local(const u16* __restrict__ qkv,
                                                    const u16* __restrict__ vT,
                                                    u16* __restrict__ out) {
    __shared__ __align__(16) u16 Kl[64][72];
    __shared__ __align__(16) u16 Vl[64][72];
    __shared__ __align__(16) u16 Pl[4][1024];
    const int tid = threadIdx.x, lane = tid & 63, wave = tid >> 6;
    const int c = lane & 15, g = lane >> 4;
    const int b = blockIdx.z, h = blockIdx.y;
    const int qbl = blockIdx.x;
    const int qb = ((qbl & 7) << 3) | (qbl >> 3);   // bijective on 0..63
    const int q0 = qb * 64;
    const int qrow = q0 + wave * 16 + c;

    short8 qf[2];
    {
        const u16* qp = qkv + (size_t)(b * S_ + qrow) * 3072 + h * 64 + g * 8;
        qf[0] = *reinterpret_cast<const short8*>(qp);
        qf[1] = *reinterpret_cast<const short8*>(qp + 32);
    }

    f32x4 acc[4];
#pragma unroll
    for (int dt = 0; dt < 4; ++dt)
#pragma unroll
        for (int j = 0; j < 4; ++j) acc[dt][j] = 0.f;
    float mrow = -1e30f, lrow = 0.f;

    const int t_lo = max(0, q0 - W_) >> 6;
    const int t_hi = min(S_ - 1, q0 + 63 + W_) >> 6;
    u16* pw = Pl[wave];

    // staging coords: thread covers rows r0 and r0+32 at col chunk cb0
    const int r0 = tid >> 3, cb0 = (tid & 7) * 8, r1 = r0 + 32;
    const u16* kbase = qkv + (size_t)b * S_ * 3072 + 1024 + h * 64 + cb0;
    const u16* vbase = vT + ((size_t)(b * H_ + h) * 64) * S_ + cb0;
    // prologue: load tile t_lo into regs
    ushort8v ka0 = *reinterpret_cast<const ushort8v*>(kbase + (size_t)(t_lo * 64 + r0) * 3072);
    ushort8v ka1 = *reinterpret_cast<const ushort8v*>(kbase + (size_t)(t_lo * 64 + r1) * 3072);
    ushort8v va0 = *reinterpret_cast<const ushort8v*>(vbase + (size_t)r0 * S_ + t_lo * 64);
    ushort8v va1 = *reinterpret_cast<const ushort8v*>(vbase + (size_t)r1 * S_ + t_lo * 64);

    for (int t = t_lo; t <= t_hi; ++t) {
        __syncthreads();   // previous compute done reading LDS
        *reinterpret_cast<ushort8v*>(&Kl[r0][cb0]) = ka0;
        *reinterpret_cast<ushort8v*>(&Kl[r1][cb0]) = ka1;
        *reinterpret_cast<ushort8v*>(&Vl[r0][cb0]) = va0;
        *reinterpret_cast<ushort8v*>(&Vl[r1][cb0]) = va1;
        if (t < t_hi) {    // issue next-tile loads; drain hides under compute below
            ka0 = *reinterpret_cast<const ushort8v*>(kbase + (size_t)((t + 1) * 64 + r0) * 3072);
            ka1 = *reinterpret_cast<const ushort8v*>(kbase + (size_t)((t + 1) * 64 + r1) * 3072);
            va0 = *reinterpret_cast<const ushort8v*>(vbase + (size_t)r0 * S_ + (t + 1) * 64);
            va1 = *reinterpret_cast<const ushort8v*>(vbase + (size_t)r1 * S_ + (t + 1) * 64);
        }
        __syncthreads();   // LDS tile t ready

        f32x4 s[4];
#pragma unroll
        for (int nt = 0; nt < 4; ++nt)
#pragma unroll
            for (int j = 0; j < 4; ++j) s[nt][j] = 0.f;
        __builtin_amdgcn_s_setprio(1);
#pragma unroll
        for (int kc = 0; kc < 2; ++kc) {
#pragma unroll
            for (int nt = 0; nt < 4; ++nt) {
                short8 kf = *reinterpret_cast<const short8*>(&Kl[nt * 16 + c][kc * 32 + g * 8]);
                s[nt] = __builtin_amdgcn_mfma_f32_16x16x32_bf16(kf, qf[kc], s[nt], 0, 0, 0);
            }
        }
        __builtin_amdgcn_s_setprio(0);

        float p[4][4];
        float tmax = -1e30f;
#pragma unroll
        for (int nt = 0; nt < 4; ++nt)
#pragma unroll
            for (int j = 0; j < 4; ++j) {
                float sv = s[nt][j] * 0.125f;
                int key = t * 64 + nt * 16 + 4 * g + j;
                bool val = (key >= qrow - W_) && (key <= qrow + W_);
                sv = val ? sv : -1e30f;
                p[nt][j] = sv;
                tmax = fmaxf(tmax, sv);
            }
        tmax = fmaxf(tmax, __shfl_xor(tmax, 16));
        tmax = fmaxf(tmax, __shfl_xor(tmax, 32));
        float mnew = fmaxf(mrow, tmax);
        float fac = __expf(mrow - mnew);
        mrow = mnew;
        float psum = 0.f;
#pragma unroll
        for (int nt = 0; nt < 4; ++nt)
#pragma unroll
            for (int j = 0; j < 4; ++j) {
                p[nt][j] = __expf(p[nt][j] - mnew);
                psum += p[nt][j];
            }
        lrow = lrow * fac + psum;
#pragma unroll
        for (int dt = 0; dt < 4; ++dt)
#pragma unroll
            for (int j = 0; j < 4; ++j) acc[dt][j] *= fac;

#pragma unroll
        for (int nt = 0; nt < 4; ++nt)
#pragma unroll
            for (int jp = 0; jp < 2; ++jp) {
                u32 pk = (u32)f2b(p[nt][2 * jp]) | ((u32)f2b(p[nt][2 * jp + 1]) << 16);
                int byteoff = (c << 7) + ((nt * 32 + 8 * g + 4 * jp) ^ ((c & 7) << 4));
                *reinterpret_cast<u32*>(reinterpret_cast<char*>(pw) + byteoff) = pk;
            }
        asm volatile("s_waitcnt lgkmcnt(0)" ::: "memory");

        __builtin_amdgcn_s_setprio(1);
#pragma unroll
        for (int h2 = 0; h2 < 2; ++h2) {
            int rb = (c << 7) + ((h2 * 64 + g * 16) ^ ((c & 7) << 4));
            short8 pa = *reinterpret_cast<const short8*>(reinterpret_cast<char*>(pw) + rb);
#pragma unroll
            for (int dt = 0; dt < 4; ++dt) {
                short8 vf = *reinterpret_cast<const short8*>(&Vl[dt * 16 + c][h2 * 32 + g * 8]);
                acc[dt] = __builtin_amdgcn_mfma_f32_16x16x32_bf16(vf, pa, acc[dt], 0, 0, 0);
            }
        }
        __builtin_amdgcn_s_setprio(0);
    }

    float lfull = lrow + __shfl_xor(lrow, 16);
    lfull += __shfl_xor(lfull, 32);
    const float rinv = 1.0f / lfull;

#pragma unroll
    for (int dt = 0; dt < 4; ++dt) {
        u32 w0 = (u32)f2b(acc[dt][0] * rinv) | ((u32)f2b(acc[dt][1] * rinv) << 16);
        u32 w1 = (u32)f2b(acc[dt][2] * rinv) | ((u32)f2b(acc[dt][3] * rinv) << 16);
        uint2 wv; wv.x = w0; wv.y = w1;
        *reinterpret_cast<uint2*>(out + (size_t)(b * S_ + qrow) * 1024 + h * 64 + dt * 16 + 4 * g) = wv;
    }
}

// ---------------- GLOBAL heads: split-KV partial flash ----------------
// grid (HG*NCH, S/64, B): x = (hh,ch) -> each KV chunk pins to one XCD's L2.
// T14 async-stage as in local.
__global__ __launch_bounds__(256) void k_attn_global_part(const u16* __restrict__ qkv,
                                                          const u16* __restrict__ vT,
                                                          const float* __restrict__ mask,
                                                          float* __restrict__ po,
                                                          float* __restrict__ ml) {
    __shared__ __align__(16) u16 Kl[64][72];
    __shared__ __align__(16) u16 Vl[64][72];
    __shared__ __align__(16) u16 Pl[4][1024];
    __shared__ float maskl[64];
    const int tid = threadIdx.x, lane = tid & 63, wave = tid >> 6;
    const int c = lane & 15, g = lane >> 4;
    const int b = blockIdx.z;
    const int hh = blockIdx.x >> 2, ch = blockIdx.x & 3;
    const int h = HL_ + hh;
    const int qb = blockIdx.y;
    const int q0 = qb * 64;
    const int qrow = q0 + wave * 16 + c;

    short8 qf[2];
    {
        const u16* qp = qkv + (size_t)(b * S_ + qrow) * 3072 + h * 64 + g * 8;
        qf[0] = *reinterpret_cast<const short8*>(qp);
        qf[1] = *reinterpret_cast<const short8*>(qp + 32);
    }

    f32x4 acc[4];
#pragma unroll
    for (int dt = 0; dt < 4; ++dt)
#pragma unroll
        for (int j = 0; j < 4; ++j) acc[dt][j] = 0.f;
    float mrow = -1e30f, lrow = 0.f;
    u16* pw = Pl[wave];

    const int t_lo = ch * (S_ / 64 / NCH_), t_hi = t_lo + (S_ / 64 / NCH_) - 1;

    const int r0 = tid >> 3, cb0 = (tid & 7) * 8, r1 = r0 + 32;
    const u16* kbase = qkv + (size_t)b * S_ * 3072 + 1024 + h * 64 + cb0;
    const u16* vbase = vT + ((size_t)(b * H_ + h) * 64) * S_ + cb0;
    ushort8v ka0 = *reinterpret_cast<const ushort8v*>(kbase + (size_t)(t_lo * 64 + r0) * 3072);
    ushort8v ka1 = *reinterpret_cast<const ushort8v*>(kbase + (size_t)(t_lo * 64 + r1) * 3072);
    ushort8v va0 = *reinterpret_cast<const ushort8v*>(vbase + (size_t)r0 * S_ + t_lo * 64);
    ushort8v va1 = *reinterpret_cast<const ushort8v*>(vbase + (size_t)r1 * S_ + t_lo * 64);
    float mk = (tid < 64) ? mask[(size_t)b * S_ + t_lo * 64 + tid] : 0.f;

    for (int t = t_lo; t <= t_hi; ++t) {
        __syncthreads();
        *reinterpret_cast<ushort8v*>(&Kl[r0][cb0]) = ka0;
        *reinterpret_cast<ushort8v*>(&Kl[r1][cb0]) = ka1;
        *reinterpret_cast<ushort8v*>(&Vl[r0][cb0]) = va0;
        *reinterpret_cast<ushort8v*>(&Vl[r1][cb0]) = va1;
        if (tid < 64) maskl[tid] = mk * (-1000.0f);
        if (t < t_hi) {
            ka0 = *reinterpret_cast<const ushort8v*>(kbase + (size_t)((t + 1) * 64 + r0) * 3072);
            ka1 = *reinterpret_cast<const ushort8v*>(kbase + (size_t)((t + 1) * 64 + r1) * 3072);
            va0 = *reinterpret_cast<const ushort8v*>(vbase + (size_t)r0 * S_ + (t + 1) * 64);
            va1 = *reinterpret_cast<const ushort8v*>(vbase + (size_t)r1 * S_ + (t + 1) * 64);
            if (tid < 64) mk = mask[(size_t)b * S_ + (t + 1) * 64 + tid];
        }
        __syncthreads();

        f32x4 s[4];
#pragma unroll
        for (int nt = 0; nt < 4; ++nt)
#pragma unroll
            for (int j = 0; j < 4; ++j) s[nt][j] = 0.f;
        __builtin_amdgcn_s_setprio(1);
#pragma unroll
        for (int kc = 0; kc < 2; ++kc) {
#pragma unroll
            for (int nt = 0; nt < 4; ++nt) {
                short8 kf = *reinterpret_cast<const short8*>(&Kl[nt * 16 + c][kc * 32 + g * 8]);
                s[nt] = __builtin_amdgcn_mfma_f32_16x16x32_bf16(kf, qf[kc], s[nt], 0, 0, 0);
            }
        }
        __builtin_amdgcn_s_setprio(0);

        float p[4][4];
        float tmax = -1e30f;
#pragma unroll
        for (int nt = 0; nt < 4; ++nt)
#pragma unroll
            for (int j = 0; j < 4; ++j) {
                float sv = s[nt][j] * 0.125f + maskl[nt * 16 + 4 * g + j];
                p[nt][j] = sv;
                tmax = fmaxf(tmax, sv);
            }
        tmax = fmaxf(tmax, __shfl_xor(tmax, 16));
        tmax = fmaxf(tmax, __shfl_xor(tmax, 32));
        float mnew = fmaxf(mrow, tmax);
        float fac = __expf(mrow - mnew);
        mrow = mnew;
        float psum = 0.f;
#pragma unroll
        for (int nt = 0; nt < 4; ++nt)
#pragma unroll
            for (int j = 0; j < 4; ++j) {
                p[nt][j] = __expf(p[nt][j] - mnew);
                psum += p[nt][j];
            }
        lrow = lrow * fac + psum;
#pragma unroll
        for (int dt = 0; dt < 4; ++dt)
#pragma unroll
            for (int j = 0; j < 4; ++j) acc[dt][j] *= fac;

#pragma unroll
        for (int nt = 0; nt < 4; ++nt)
#pragma unroll
            for (int jp = 0; jp < 2; ++jp) {
                u32 pk = (u32)f2b(p[nt][2 * jp]) | ((u32)f2b(p[nt][2 * jp + 1]) << 16);
                int byteoff = (c << 7) + ((nt * 32 + 8 * g + 4 * jp) ^ ((c & 7) << 4));
                *reinterpret_cast<u32*>(reinterpret_cast<char*>(pw) + byteoff) = pk;
            }
        asm volatile("s_waitcnt lgkmcnt(0)" ::: "memory");

        __builtin_amdgcn_s_setprio(1);
#pragma unroll
        for (int h2 = 0; h2 < 2; ++h2) {
            int rb = (c << 7) + ((h2 * 64 + g * 16) ^ ((c & 7) << 4));
            short8 pa = *reinterpret_cast<const short8*>(reinterpret_cast<char*>(pw) + rb);
#pragma unroll
            for (int dt = 0; dt < 4; ++dt) {
                short8 vf = *reinterpret_cast<const short8*>(&Vl[dt * 16 + c][h2 * 32 + g * 8]);
                acc[dt] = __builtin_amdgcn_mfma_f32_16x16x32_bf16(vf, pa, acc[dt], 0, 0, 0);
            }
        }
        __builtin_amdgcn_s_setprio(0);
    }

    float lfull = lrow + __shfl_xor(lrow, 16);
    lfull += __shfl_xor(lfull, 32);

    float* po_blk = po + ((((size_t)(b * HG_ + hh) * NCH_ + ch) * (S_ / 64) + qb) * 4096);
    const int ql = wave * 16 + c;
#pragma unroll
    for (int dt = 0; dt < 4; ++dt)
        *reinterpret_cast<f32x4*>(po_blk + ql * 64 + dt * 16 + 4 * g) = acc[dt];
    if (g == 0) {
        size_t mb = (((size_t)(b * HG_ + hh) * NCH_ + ch) * S_ + q0 + ql) * 2;
        ml[mb] = mrow;
        ml[mb + 1] = lfull;
    }
}

// ---------------- merge split-KV partials -> bf16 attn output ----------------
__global__ __launch_bounds__(256) void k_attn_merge(const float* __restrict__ po,
                                                    const float* __restrict__ ml,
                                                    u16* __restrict__ out) {
    const int qb = blockIdx.x, hh = blockIdx.y, b = blockIdx.z;
    const int t = threadIdx.x;
    const int ql = t >> 2, d0 = (t & 3) * 16;
    const int q = qb * 64 + ql;

    float mv[NCH_], lv[NCH_];
    float M = -1e30f;
#pragma unroll
    for (int ch = 0; ch < NCH_; ++ch) {
        size_t mb = (((size_t)(b * HG_ + hh) * NCH_ + ch) * S_ + q) * 2;
        mv[ch] = ml[mb];
        lv[ch] = ml[mb + 1];
        M = fmaxf(M, mv[ch]);
    }
    float wch[NCH_], L = 0.f;
#pragma unroll
    for (int ch = 0; ch < NCH_; ++ch) {
        wch[ch] = __expf(mv[ch] - M);
        L += wch[ch] * lv[ch];
    }
    const float rL = 1.0f / L;

    float o[16];
#pragma unroll
    for (int i = 0; i < 16; ++i) o[i] = 0.f;
#pragma unroll
    for (int ch = 0; ch < NCH_; ++ch) {
        const float* pb = po + ((((size_t)(b * HG_ + hh) * NCH_ + ch) * (S_ / 64) + qb) * 4096) + ql * 64 + d0;
        const float w = wch[ch];
#pragma unroll
        for (int i = 0; i < 4; ++i) {
            float4 v = reinterpret_cast<const float4*>(pb)[i];
            o[4 * i + 0] += w * v.x; o[4 * i + 1] += w * v.y;
            o[4 * i + 2] += w * v.z; o[4 * i + 3] += w * v.w;
        }
    }
    ushort8v r0, r1;
#pragma unroll
    for (int i = 0; i < 8; ++i) { r0[i] = f2b(o[i] * rL); r1[i] = f2b(o[8 + i] * rL); }
    u16* op = out + (size_t)(b * S_ + q) * 1024 + (HL_ + hh) * 64 + d0;
    *reinterpret_cast<ushort8v*>(op) = r0;
    *reinterpret_cast<ushort8v*>(op + 8) = r1;
}

// ---------------- fused residual + LayerNorm (row = 1024), bf16 delta/base paths ----------------
template <bool BASEF>
__global__ __launch_bounds__(256) void k_ln(const float* __restrict__ basef, const u16* __restrict__ baseb,
                                            const u16* __restrict__ delta,
                                            const float* __restrict__ g, const float* __restrict__ bt,
                                            float* __restrict__ outf, u16* __restrict__ outb) {
    __shared__ float red[8];
    const int row = blockIdx.x, tid = threadIdx.x;
    const int lane = tid & 63, wave = tid >> 6;
    float x0, x1, x2, x3;
    if (BASEF) {
        float4 xb = reinterpret_cast<const float4*>(basef + (size_t)row * 1024)[tid];
        x0 = xb.x; x1 = xb.y; x2 = xb.z; x3 = xb.w;
    } else {
        ushort4v xb = reinterpret_cast<const ushort4v*>(baseb + (size_t)row * 1024)[tid];
        x0 = b2f(xb[0]); x1 = b2f(xb[1]); x2 = b2f(xb[2]); x3 = b2f(xb[3]);
    }
    ushort4v xd = reinterpret_cast<const ushort4v*>(delta + (size_t)row * 1024)[tid];
    x0 += b2f(xd[0]); x1 += b2f(xd[1]); x2 += b2f(xd[2]); x3 += b2f(xd[3]);
    float s = x0 + x1 + x2 + x3;
#pragma unroll
    for (int off = 32; off >= 1; off >>= 1) s += __shfl_xor(s, off);
    if (lane == 0) red[wave] = s;
    __syncthreads();
    float mu = (red[0] + red[1] + red[2] + red[3]) * (1.f / 1024.f);
    float d0 = x0 - mu, d1 = x1 - mu, d2 = x2 - mu, d3 = x3 - mu;
    float s2 = d0 * d0 + d1 * d1 + d2 * d2 + d3 * d3;
#pragma unroll
    for (int off = 32; off >= 1; off >>= 1) s2 += __shfl_xor(s2, off);
    if (lane == 0) red[4 + wave] = s2;
    __syncthreads();
    float var = (red[4] + red[5] + red[6] + red[7]) * (1.f / 1024.f);
    float rs = rsqrtf(var + 1e-6f);
    float4 gv = reinterpret_cast<const float4*>(g)[tid];
    float4 bv = reinterpret_cast<const float4*>(bt)[tid];
    float o0 = d0 * rs * gv.x + bv.x;
    float o1 = d1 * rs * gv.y + bv.y;
    float o2 = d2 * rs * gv.z + bv.z;
    float o3 = d3 * rs * gv.w + bv.w;
    if (outf) {
        float4 ov; ov.x = o0; ov.y = o1; ov.z = o2; ov.w = o3;
        reinterpret_cast<float4*>(outf + (size_t)row * 1024)[tid] = ov;
    }
    if (outb) {
        ushort4v ob; ob[0] = f2b(o0); ob[1] = f2b(o1); ob[2] = f2b(o2); ob[3] = f2b(o3);
        reinterpret_cast<ushort4v*>(outb + (size_t)row * 1024)[tid] = ob;
    }
}

extern "C" void kernel_launch(void* const* d_in, const int* in_sizes, int n_in,
                              void* d_out, int out_size, void* d_ws, size_t ws_size,
                              hipStream_t stream) {
    const float* x    = (const float*)d_in[0];
    const float* mask = (const float*)d_in[1];
    const float* wq   = (const float*)d_in[2];
    const float* wq_b = (const float*)d_in[3];
    const float* wk   = (const float*)d_in[4];
    const float* wk_b = (const float*)d_in[5];
    const float* wv   = (const float*)d_in[6];
    const float* wv_b = (const float*)d_in[7];
    const float* wo   = (const float*)d_in[8];
    const float* wo_b = (const float*)d_in[9];
    const float* w1   = (const float*)d_in[10];
    const float* b1   = (const float*)d_in[11];
    const float* w2   = (const float*)d_in[12];
    const float* b2   = (const float*)d_in[13];
    const float* ln1g = (const float*)d_in[14];
    const float* ln1b = (const float*)d_in[15];
    const float* ln2g = (const float*)d_in[16];
    const float* ln2b = (const float*)d_in[17];
    float* out = (float*)d_out;

    char* ws = (char*)d_ws;
    const size_t MB = 1024ull * 1024ull;
    u16*   qkv_b  = (u16*)(ws + 0);
    u16*   h_b    = (u16*)(ws + 0);
    u16*   vTb    = (u16*)(ws + 64 * MB);
    u16*   ybuf_b = (u16*)(ws + 64 * MB);
    u16*   ffn2_b = (u16*)(ws + 64 * MB);
    float* po     = (float*)(ws + 96 * MB);
    float* ml     = (float*)(ws + 113 * MB);
    u16*   xb     = (u16*)(ws + 128 * MB);
    u16*   attn_b = (u16*)(ws + 128 * MB);
    u16*   out1_b = (u16*)(ws + 128 * MB);
    u16*   wT     = (u16*)(ws + 144 * MB);
    float* bias3  = (float*)(ws + 152 * MB);

    const dim3 tb(256);

    // x -> bf16
    k_f32_to_bf16<<<(M_ * D_ / 4 + 255) / 256, tb, 0, stream>>>(x, xb, M_ * D_ / 4);
    // pack W_qkv^T bf16 [3072][1024] (one fused launch) + bias
    k_transpose3<<<dim3(32, 32, 3), tb, 0, stream>>>(wq, wk, wv, wT);
    k_pack_bias3<<<12, tb, 0, stream>>>(wq_b, wk_b, wv_b, bias3);
    // QKV: [8192,3072] bf16
    k_gemm<false, false, true><<<dim3(M_ / 128, 3072 / 128), tb, 0, stream>>>(
        xb, wT, bias3, nullptr, qkv_b, M_, 3072, 1024);
    // V pre-transpose for attention PV
    k_transpose_v<<<dim3(S_ / 32, 2, B_ * H_), tb, 0, stream>>>(qkv_b, vTb);
    // attention -> attn_b bf16 [B,S,H,64]
    k_attn_local<<<dim3(S_ / 64, HL_, B_), tb, 0, stream>>>(qkv_b, vTb, attn_b);
    k_attn_global_part<<<dim3(HG_ * NCH_, S_ / 64, B_), tb, 0, stream>>>(qkv_b, vTb, mask, po, ml);
    k_attn_merge<<<dim3(S_ / 64, HG_, B_), tb, 0, stream>>>(po, ml, attn_b);
    // output projection -> bf16 delta
    k_transpose_bf16<<<dim3(32, 32), tb, 0, stream>>>(wo, wT, 1024, 1024, 0);
    k_gemm<false, false, true><<<dim3(M_ / 128, 1024 / 128), tb, 0, stream>>>(
        attn_b, wT, wo_b, nullptr, ybuf_b, M_, 1024, 1024);
    // LN1 (residual x f32 + bf16 delta) -> out1 bf16 only
    k_ln<true><<<M_, tb, 0, stream>>>(x, nullptr, ybuf_b, ln1g, ln1b, nullptr, out1_b);
    // FFN1 (leaky relu 0.2) -> h bf16
    k_transpose_bf16<<<dim3(128, 32), tb, 0, stream>>>(w1, wT, 1024, 4096, 0);
    k_gemm<true, false, true><<<dim3(M_ / 128, 4096 / 128), tb, 0, stream>>>(
        out1_b, wT, b1, nullptr, h_b, M_, 4096, 1024);
    // FFN2 -> bf16 delta
    k_transpose_bf16<<<dim3(32, 128), tb, 0, stream>>>(w2, wT, 4096, 1024, 0);
    k_gemm<false, false, true><<<dim3(M_ / 128, 1024 / 128), tb, 0, stream>>>(
        h_b, wT, b2, nullptr, ffn2_b, M_, 1024, 4096);
    // LN2 (residual out1 bf16 + bf16 delta) -> final output f32
    k_ln<false><<<M_, tb, 0, stream>>>(nullptr, out1_b, ffn2_b, ln2g, ln2b, out, nullptr);
}